// Round 1
// baseline (166.802 us; speedup 1.0000x reference)
//
#include <hip/hip_runtime.h>
#include <hip/hip_bf16.h>

// Problem constants (fixed by setup_inputs)
#define NSAMP 16384   // N
#define BB    4       // batch
#define C2D   128
#define C3D   128
#define HH    96
#define WW    160
#define COUT  128
#define HW    (HH*WW) // 15360
#define TN    32      // samples per fuse block
#define PROW  136     // LDS row stride in bf16 elems: 128 + 8 pad = 68 words (== 4 mod 32
                      // -> conflict-free b128 reads/writes by 8-lane groups, 16B-aligned rows)

typedef __attribute__((ext_vector_type(8))) short bf16x8;  // 8 bf16 = 4 VGPRs (MFMA A/B frag)
typedef __attribute__((ext_vector_type(4))) float f32x4;   // MFMA C/D frag

__device__ __forceinline__ float bf16lo(unsigned int u) { return __uint_as_float(u << 16); }
__device__ __forceinline__ float bf16hi(unsigned int u) { return __uint_as_float(u & 0xffff0000u); }
__device__ __forceinline__ unsigned int pack2(float a, float b) {
    union { __hip_bfloat162 h; unsigned int u; } c;
    c.h = __float22bfloat162_rn(make_float2(a, b));   // RNE, x in low 16 bits
    return c.u;
}

// ---------------------------------------------------------------------------
// Kernel 1: W fp32 [COUT,256] -> Wb2 bf16 [COUT][c=0..127], Wb3 bf16 [COUT][c=128..255].
// Both row-major, A/B-fragment friendly (16B per lane along k).
// ---------------------------------------------------------------------------
__global__ __launch_bounds__(256) void wcvt_kernel(
    const float* __restrict__ Wm,
    unsigned short* __restrict__ Wb2, unsigned short* __restrict__ Wb3)
{
    const int i = blockIdx.x * 256 + threadIdx.x;   // float4 index, 8192 total
    const float4 v = ((const float4*)Wm)[i];
    uint2 o;
    o.x = pack2(v.x, v.y);
    o.y = pack2(v.z, v.w);
    const int co = i >> 6;        // 64 float4 per 256-col row
    const int c4 = i & 63;
    unsigned short* dst = (c4 < 32) ? (Wb2 + co * 128 + c4 * 4)
                                    : (Wb3 + co * 128 + (c4 - 32) * 4);
    *(uint2*)dst = o;
}

// ---------------------------------------------------------------------------
// Kernel 2: projected feature map (bilinear sampling commutes with W2d):
//   P[b][hw][co] = sum_c W2d[co][c] * bf16(f2d[b][c][hw]),  bf16 channel-last.
// Tile = 64 hw x 128 co per block, 960 blocks, 256 threads (4 waves).
// Stage f2d transpose into LDS [hw][c] (same traffic as the old transpose
// kernel), then MFMA 16x16x32: A = LDS hw-rows, B = Wb2 rows (L1/L2-hot).
// ---------------------------------------------------------------------------
__global__ __launch_bounds__(256, 4) void proj2d_kernel(
    const float*          __restrict__ f2d,   // [B,C2D,HW]
    const unsigned short* __restrict__ Wb2,   // [COUT][128] bf16
    unsigned short*       __restrict__ P)     // [B,HW,COUT] bf16
{
    __shared__ unsigned short t[64 * PROW];   // [hw_local][c]
    const int tid  = threadIdx.x;
    const int lane = tid & 63;
    const int wv   = tid >> 6;
    const int blk  = blockIdx.x;
    const int b    = blk / (HW / 64);
    const int hw0  = (blk % (HW / 64)) * 64;

    // ---- stage: wave wv covers channels [32wv, 32wv+32), lane = hw.
    // 8 coalesced 256B loads per group, pack to uint4, one b128 LDS write
    // (row stride 68 words == 4 mod 32 -> conflict-free per 8-lane group). ----
    const float* src = f2d + (size_t)b * C2D * HW + hw0 + lane;
    #pragma unroll
    for (int g = 0; g < 4; ++g) {
        const int c0 = wv * 32 + g * 8;
        float v[8];
        #pragma unroll
        for (int k = 0; k < 8; ++k) v[k] = src[(size_t)(c0 + k) * HW];
        uint4 pk;
        pk.x = pack2(v[0], v[1]);
        pk.y = pack2(v[2], v[3]);
        pk.z = pack2(v[4], v[5]);
        pk.w = pack2(v[6], v[7]);
        *(uint4*)&t[lane * PROW + c0] = pk;
    }
    __syncthreads();

    // ---- GEMM: D[64 hw x 128 co]; wave wv owns hw rows [16wv, 16wv+16). ----
    const int quad = lane >> 4;
    const int nloc = lane & 15;

    f32x4 acc[8];
    #pragma unroll
    for (int nt = 0; nt < 8; ++nt) acc[nt] = (f32x4){0.f, 0.f, 0.f, 0.f};

    const unsigned short* arow = &t[(wv * 16 + nloc) * PROW + quad * 8];
    const unsigned short* brow = Wb2 + nloc * 128 + quad * 8;

    #pragma unroll
    for (int ks = 0; ks < 4; ++ks) {
        const bf16x8 a = *(const bf16x8*)(arow + ks * 32);
        #pragma unroll
        for (int nt = 0; nt < 8; ++nt) {
            const bf16x8 bb = *(const bf16x8*)(brow + nt * 16 * 128 + ks * 32);
            acc[nt] = __builtin_amdgcn_mfma_f32_16x16x32_bf16(a, bb, acc[nt], 0, 0, 0);
        }
    }

    // ---- store: C/D layout col(co)=lane&15, row(hw)=quad*4+r.
    // Per instr: 4 rows x 32B contiguous runs. ----
    unsigned short* pb = P + ((size_t)b * HW + hw0 + wv * 16 + quad * 4) * C2D + nloc;
    #pragma unroll
    for (int nt = 0; nt < 8; ++nt) {
        #pragma unroll
        for (int r = 0; r < 4; ++r) {
            __hip_bfloat16 h = __float2bfloat16(acc[nt][r]);
            pb[(size_t)r * C2D + nt * 16] = *(unsigned short*)&h;
        }
    }
}

// ---------------------------------------------------------------------------
// Kernel 3: fused 3D GEMM + bilinear gather of P + bias + leaky.
// Block = 32 samples, 256 threads (4 waves), grid 2048, XCD-swizzled.
// Phase 1: stage f3d tile -> LDS [n][c] bf16 (single barrier total).
// Phase 2: MFMA K=128: A = Wb3 rows (L1-hot), B = LDS rows.
// Phase 3: gather 4 corner rows of P per sample, blend DIRECTLY into acc
//          (no pack / LDS round trip), then bias + leaky-relu + store.
// ---------------------------------------------------------------------------
__global__ __launch_bounds__(256, 6) void fuse_kernel(
    const float*          __restrict__ xy,     // [B,2,N]
    const unsigned short* __restrict__ P,      // [B,HW,COUT] bf16
    const float*          __restrict__ f3d,    // [B,C3D,N]
    const unsigned short* __restrict__ Wb3,    // [COUT][128] bf16 (c = 128..255 of W)
    const float*          __restrict__ bias,   // [COUT]
    float* __restrict__ out)                   // [B,COUT,N]
{
    __shared__ unsigned short cat3[TN * PROW]; // [n][c3] bf16
    __shared__ float4 sw4[TN];
    __shared__ int4   soff4[TN];

    const int tid  = threadIdx.x;
    const int lane = tid & 63;
    const int wv   = tid >> 6;
    // XCD-bijective swizzle (2048 % 8 == 0): consecutive tiles of one batch
    // stay on one XCD -> per-batch P slice (3.93 MB) lives in that XCD's L2.
    const int blk  = (blockIdx.x & 7) * 256 + (blockIdx.x >> 3);
    const int b    = blk >> 9;            // 512 tiles per batch
    const int n0   = (blk & 511) * TN;

    // ---- Phase 0: bilinear params (32 threads) ----
    if (tid < TN) {
        const int n = n0 + tid;
        float x = xy[((size_t)b * 2 + 0) * NSAMP + n];
        float y = xy[((size_t)b * 2 + 1) * NSAMP + n];
        float xf = floorf(x), yf = floorf(y);
        float wx1 = x - xf, wy1 = y - yf;
        float wx0 = 1.0f - wx1, wy0 = 1.0f - wy1;
        int x0 = (int)xf, y0 = (int)yf;
        int x1 = x0 + 1, y1 = y0 + 1;
        if (x0 < 0 || x0 > WW - 1) wx0 = 0.0f;
        if (x1 < 0 || x1 > WW - 1) wx1 = 0.0f;
        if (y0 < 0 || y0 > HH - 1) wy0 = 0.0f;
        if (y1 < 0 || y1 > HH - 1) wy1 = 0.0f;
        x0 = min(max(x0, 0), WW - 1);
        x1 = min(max(x1, 0), WW - 1);
        y0 = min(max(y0, 0), HH - 1);
        y1 = min(max(y1, 0), HH - 1);
        sw4[tid]   = make_float4(wx0 * wy0, wx1 * wy0, wx0 * wy1, wx1 * wy1);
        soff4[tid] = make_int4(y0 * WW + x0, y0 * WW + x1,
                               y1 * WW + x0, y1 * WW + x1);
    }

    // ---- Phase 1: f3d -> cat3[n][c], bf16. Thread = (sample s, 16 channels).
    // Coalesced 128B runs; b128 LDS writes conflict-free (stride 68w). ----
    {
        const int s  = tid & 31;
        const int cg = tid >> 5;          // 0..7 -> channels [16cg, 16cg+16)
        const float* p3 = f3d + ((size_t)(b * C3D + cg * 16)) * NSAMP + n0 + s;
        float v[16];
        #pragma unroll
        for (int k = 0; k < 16; ++k) v[k] = p3[(size_t)k * NSAMP];
        uint4 pk0, pk1;
        pk0.x = pack2(v[0],  v[1]);  pk0.y = pack2(v[2],  v[3]);
        pk0.z = pack2(v[4],  v[5]);  pk0.w = pack2(v[6],  v[7]);
        pk1.x = pack2(v[8],  v[9]);  pk1.y = pack2(v[10], v[11]);
        pk1.z = pack2(v[12], v[13]); pk1.w = pack2(v[14], v[15]);
        *(uint4*)&cat3[s * PROW + cg * 16]     = pk0;
        *(uint4*)&cat3[s * PROW + cg * 16 + 8] = pk1;
    }
    __syncthreads();   // single barrier: phase 2/3 read cat3 + sw4/soff4

    const int quad = lane >> 4;
    const int nloc = lane & 15;

    f32x4 acc[2][2];
    #pragma unroll
    for (int mt = 0; mt < 2; ++mt)
        #pragma unroll
        for (int nt = 0; nt < 2; ++nt)
            acc[mt][nt] = (f32x4){0.f, 0.f, 0.f, 0.f};

    // ---- Phase 2: MFMA GEMM, D[co 32-slice x 32 samples], K = 128 ----
    {
        // A-frag: row co = 32wv + 16mt + nloc, k = 32ks + 8quad + j
        const unsigned short* wb0 = Wb3 + (wv * 32 + nloc) * 128 + quad * 8;
        #pragma unroll
        for (int ks = 0; ks < 4; ++ks) {
            const int k0 = ks * 32;
            const bf16x8 a0 = *(const bf16x8*)(wb0 + k0);
            const bf16x8 a1 = *(const bf16x8*)(wb0 + 16 * 128 + k0);
            #pragma unroll
            for (int nt = 0; nt < 2; ++nt) {
                const bf16x8 bfrag = *(const bf16x8*)
                    &cat3[(nt * 16 + nloc) * PROW + k0 + quad * 8];
                acc[0][nt] = __builtin_amdgcn_mfma_f32_16x16x32_bf16(
                    a0, bfrag, acc[0][nt], 0, 0, 0);
                acc[1][nt] = __builtin_amdgcn_mfma_f32_16x16x32_bf16(
                    a1, bfrag, acc[1][nt], 0, 0, 0);
            }
        }
    }

    // ---- Phase 3: gather-blend P corner rows straight into acc.
    // Lane (quad,nloc) owns co = [cobase, cobase+4) of sample n = 16nt+nloc;
    // 8B load per corner per cell (32B runs across quads, L2-hot). ----
    {
        const unsigned short* pb = P + (size_t)b * HW * C2D;
        #pragma unroll
        for (int nt = 0; nt < 2; ++nt) {
            const int j = nt * 16 + nloc;
            const float4 w = sw4[j];
            const int4   o = soff4[j];
            #pragma unroll
            for (int mt = 0; mt < 2; ++mt) {
                const int cobase = wv * 32 + mt * 16 + quad * 4;
                const unsigned short* pc = pb + cobase;
                const uint2 c0v = *(const uint2*)(pc + (size_t)o.x * C2D);
                const uint2 c1v = *(const uint2*)(pc + (size_t)o.y * C2D);
                const uint2 c2v = *(const uint2*)(pc + (size_t)o.z * C2D);
                const uint2 c3v = *(const uint2*)(pc + (size_t)o.w * C2D);
                acc[mt][nt][0] += w.x * bf16lo(c0v.x) + w.y * bf16lo(c1v.x)
                                + w.z * bf16lo(c2v.x) + w.w * bf16lo(c3v.x);
                acc[mt][nt][1] += w.x * bf16hi(c0v.x) + w.y * bf16hi(c1v.x)
                                + w.z * bf16hi(c2v.x) + w.w * bf16hi(c3v.x);
                acc[mt][nt][2] += w.x * bf16lo(c0v.y) + w.y * bf16lo(c1v.y)
                                + w.z * bf16lo(c2v.y) + w.w * bf16lo(c3v.y);
                acc[mt][nt][3] += w.x * bf16hi(c0v.y) + w.y * bf16hi(c1v.y)
                                + w.z * bf16hi(c2v.y) + w.w * bf16hi(c3v.y);
            }
        }
    }

    // ---- Epilogue: bias + leaky-relu; C/D layout col=lane&15, row=quad*4+r ----
    #pragma unroll
    for (int mt = 0; mt < 2; ++mt) {
        const int cobase = wv * 32 + mt * 16 + quad * 4;
        float bv[4];
        #pragma unroll
        for (int r = 0; r < 4; ++r) bv[r] = bias[cobase + r];
        #pragma unroll
        for (int nt = 0; nt < 2; ++nt) {
            float* po = out + (size_t)(b * COUT + cobase) * NSAMP
                      + n0 + nt * 16 + nloc;
            #pragma unroll
            for (int r = 0; r < 4; ++r) {
                float yv = acc[mt][nt][r] + bv[r];
                yv = (yv >= 0.0f) ? yv : 0.1f * yv;
                po[(size_t)r * NSAMP] = yv;
            }
        }
    }
}

extern "C" void kernel_launch(void* const* d_in, const int* in_sizes, int n_in,
                              void* d_out, int out_size, void* d_ws, size_t ws_size,
                              hipStream_t stream) {
    const float* xy   = (const float*)d_in[0];
    const float* f2d  = (const float*)d_in[1];
    const float* f3d  = (const float*)d_in[2];
    const float* Wm   = (const float*)d_in[3];
    const float* bias = (const float*)d_in[4];
    float* out = (float*)d_out;

    // ws layout: P bf16 [B*HW*COUT] (15.73 MB), then Wb2, Wb3 (32 KB each)
    unsigned short* P   = (unsigned short*)d_ws;
    unsigned short* Wb2 = P + (size_t)BB * HW * C2D;
    unsigned short* Wb3 = Wb2 + (size_t)COUT * 128;

    wcvt_kernel<<<dim3((COUT * 256 / 4) / 256), 256, 0, stream>>>(Wm, Wb2, Wb3);
    proj2d_kernel<<<dim3(BB * (HW / 64)), 256, 0, stream>>>(f2d, Wb2, P);
    fuse_kernel<<<dim3(BB * (NSAMP / TN)), 256, 0, stream>>>(
        xy, P, f3d, Wb3, bias, out);
}

// Round 4
// 135.452 us; speedup vs baseline: 1.2314x; 1.2314x over previous
//
#include <hip/hip_runtime.h>
#include <hip/hip_bf16.h>

// Problem constants (fixed by setup_inputs)
#define NSAMP 16384   // N
#define BB    4       // batch
#define C2D   128
#define C3D   128
#define HH    96
#define WW    160
#define COUT  128
#define KK    256     // fan_in
#define HW    (HH*WW) // 15360
#define TN    64      // samples per fuse block
#define CATS  264     // cat row stride bf16: word stride 132 == 4 (mod 32) -> 2-way (free)
                      // on b128 quarter-wave access, 16B-aligned rows
#define TS    136     // transpose LDS row stride shorts: word stride 68

typedef __attribute__((ext_vector_type(8))) short bf16x8;  // 8 bf16 = 4 VGPRs (MFMA A/B frag)
typedef __attribute__((ext_vector_type(4))) float f32x4;   // MFMA C/D frag

__device__ __forceinline__ float bf16lo(unsigned int u) { return __uint_as_float(u << 16); }
__device__ __forceinline__ float bf16hi(unsigned int u) { return __uint_as_float(u & 0xffff0000u); }
__device__ __forceinline__ unsigned int pack2(float a, float b) {
    union { __hip_bfloat162 h; unsigned int u; } c;
    c.h = __float22bfloat162_rn(make_float2(a, b));   // RNE, x in low 16 bits
    return c.u;
}

// ---------------------------------------------------------------------------
// Kernel 1: W fp32 [COUT,KK] -> bf16 row-major (A-fragment-friendly).
// ---------------------------------------------------------------------------
__global__ __launch_bounds__(256) void wcvt_kernel(
    const float* __restrict__ Wm, unsigned short* __restrict__ Wb)
{
    const int i = blockIdx.x * 256 + threadIdx.x;   // 8192 threads x 4 elems
    const float4 v = ((const float4*)Wm)[i];
    uint2 o;
    o.x = pack2(v.x, v.y);
    o.y = pack2(v.z, v.w);
    ((uint2*)Wb)[i] = o;
}

// ---------------------------------------------------------------------------
// Kernel 2: f2d fp32 [B,C2D,H,W] -> f2dt bf16 channel-last [B,HW,C2D].
// Tile = 128 hw x 128 c, 512 threads, 480 blocks (XCD-swizzled).
// Reads: 512-B granule per channel row (2 x 256B adjacent instrs).
// Writes: fully contiguous 32-KB tile, uint4 (full 256-B rows).
// LDS word layout: word(row, w) = row*68 + (w ^ xk(row)), xk = 4*((row>>3)&7).
//   stage b32 writes: the 8 lanes sharing (4*lane mod 32) get 8 distinct XOR
//   keys -> conflict-free (was 8-way without swizzle).
//   readout b128: XOR key is row-constant, multiple of 4 words -> 16B-aligned,
//   column permutation within {0..60} -> conflict-free.
// ---------------------------------------------------------------------------
__global__ __launch_bounds__(512) void transpose_cvt_kernel(
    const float* __restrict__ f2d, unsigned short* __restrict__ f2dt)
{
    __shared__ unsigned short t[128 * TS];   // 34816 B
    unsigned int* tw = (unsigned int*)t;
    const int tid  = threadIdx.x;
    const int lane = tid & 63;
    const int wv   = tid >> 6;               // 0..7: channels [16wv, 16wv+16)
    const int blk  = (blockIdx.x & 7) * 60 + (blockIdx.x >> 3);  // 480 % 8 == 0
    const int b    = blk / 120;
    const int hw0  = (blk % 120) * 128;

    const int xk = 4 * ((lane >> 3) & 7);    // row-XOR key (rows lane, lane+64 share it)
    const float* src = f2d + (size_t)b * C2D * HW + hw0 + lane;
    #pragma unroll
    for (int st = 0; st < 8; ++st) {
        const int c = wv * 16 + st * 2;
        const float va0 = src[(size_t)c * HW];
        const float vb0 = src[(size_t)(c + 1) * HW];
        const float va1 = src[(size_t)c * HW + 64];
        const float vb1 = src[(size_t)(c + 1) * HW + 64];
        const int w = (c >> 1) ^ xk;
        tw[lane        * (TS / 2) + w] = pack2(va0, vb0);
        tw[(lane + 64) * (TS / 2) + w] = pack2(va1, vb1);
    }
    __syncthreads();
    #pragma unroll
    for (int it = 0; it < 4; ++it) {
        const int r  = it * 32 + (tid >> 4);
        const int rk = 4 * ((r >> 3) & 7);
        const uint4 v = *(const uint4*)&tw[r * (TS / 2) + (((tid & 15) * 4) ^ rk)];
        *(uint4*)&f2dt[((size_t)b * HW + hw0 + r) * C2D + (tid & 15) * 8] = v;
    }
}

// ---------------------------------------------------------------------------
// Kernel 3 helper: blend 4 gathered corner fragments (4 channels each) and
// write the packed bf16 result into the cat LDS row. (Function, not macro:
// a macro parameter named `w` would collide with float4's `.w` member.)
// ---------------------------------------------------------------------------
__device__ __forceinline__ void blend_write(
    const uint2* cv, const float4 bw, unsigned int* catw, int row, int ch4)
{
    float r0 = bw.x * bf16lo(cv[0].x) + bw.y * bf16lo(cv[1].x)
             + bw.z * bf16lo(cv[2].x) + bw.w * bf16lo(cv[3].x);
    float r1 = bw.x * bf16hi(cv[0].x) + bw.y * bf16hi(cv[1].x)
             + bw.z * bf16hi(cv[2].x) + bw.w * bf16hi(cv[3].x);
    float r2 = bw.x * bf16lo(cv[0].y) + bw.y * bf16lo(cv[1].y)
             + bw.z * bf16lo(cv[2].y) + bw.w * bf16lo(cv[3].y);
    float r3 = bw.x * bf16hi(cv[0].y) + bw.y * bf16hi(cv[1].y)
             + bw.z * bf16hi(cv[2].y) + bw.w * bf16hi(cv[3].y);
    uint2 pk;
    pk.x = pack2(r0, r1);
    pk.y = pack2(r2, r3);
    *(uint2*)&catw[row * (CATS / 2) + (ch4 >> 1)] = pk;
}

// ---------------------------------------------------------------------------
// Kernel 3: fused bilinear-gather + concat + bf16 MFMA GEMM + bias + leaky.
// 512 threads (8 waves), TN=64, grid 1024, XCD-swizzled.
// Wave wv: gathers samples [8wv, 8wv+8); GEMM tile co [32(wv&3), +32) x
// samples [32(wv>>2), +32). Split-K pipeline: GEMM k-half2 (f3d) runs while
// gather batch A is in flight; batch B issued under blend of A.
// launch_bounds (512,4): VGPR cap 128 -> no spills for the ~80 live regs at
// the gather/pack overlap; LDS (33.8 KB) bounds residency at 2 blocks/CU.
// ---------------------------------------------------------------------------
__global__ __launch_bounds__(512, 4) void fuse_kernel(
    const float*          __restrict__ xy,     // [B,2,N]
    const unsigned short* __restrict__ f2dt,   // [B,HW,C2D] bf16
    const float*          __restrict__ f3d,    // [B,C3D,N]
    const unsigned short* __restrict__ Wb,     // [COUT,KK] bf16
    const float*          __restrict__ bias,   // [COUT]
    float* __restrict__ out)                   // [B,COUT,N]
{
    __shared__ unsigned short cat[TN * CATS];  // 33792 B
    unsigned int* catw = (unsigned int*)cat;

    const int tid  = threadIdx.x;
    const int lane = tid & 63;
    const int wv   = tid >> 6;                 // 0..7
    // XCD-bijective swizzle (1024 % 8 == 0): one XCD's blocks stay in one
    // batch -> f2dt slice (3.93 MB) resident in that XCD's 4-MB L2.
    const int blk  = (blockIdx.x & 7) * 128 + (blockIdx.x >> 3);
    const int b    = blk >> 8;                 // 256 tiles per batch
    const int n0   = (blk & 255) * TN;

    // ---- bilinear params in registers (no LDS, no barrier):
    // lane L holds params of sample wv*8 + (L&7) ----
    float w4x, w4y, w4z, w4w;
    int   o4x, o4y, o4z, o4w;
    {
        const int n = n0 + wv * 8 + (lane & 7);
        float x = xy[((size_t)b * 2 + 0) * NSAMP + n];
        float y = xy[((size_t)b * 2 + 1) * NSAMP + n];
        float xf = floorf(x), yf = floorf(y);
        float wx1 = x - xf, wy1 = y - yf;
        float wx0 = 1.0f - wx1, wy0 = 1.0f - wy1;
        int x0 = (int)xf, y0 = (int)yf;
        int x1 = x0 + 1, y1 = y0 + 1;
        if (x0 < 0 || x0 > WW - 1) wx0 = 0.0f;
        if (x1 < 0 || x1 > WW - 1) wx1 = 0.0f;
        if (y0 < 0 || y0 > HH - 1) wy0 = 0.0f;
        if (y1 < 0 || y1 > HH - 1) wy1 = 0.0f;
        x0 = min(max(x0, 0), WW - 1);
        x1 = min(max(x1, 0), WW - 1);
        y0 = min(max(y0, 0), HH - 1);
        y1 = min(max(y1, 0), HH - 1);
        w4x = wx0 * wy0; w4y = wx1 * wy0; w4z = wx0 * wy1; w4w = wx1 * wy1;
        o4x = y0 * WW + x0; o4y = y0 * WW + x1;
        o4z = y1 * WW + x0; o4w = y1 * WW + x1;
    }

    // ---- f3d loads issue first (HBM latency ~900 cyc) ----
    float v3[16];
    {
        const float* p3 = f3d + ((size_t)(b * C3D + wv * 16)) * NSAMP + n0 + lane;
        #pragma unroll
        for (int t = 0; t < 16; ++t) v3[t] = p3[(size_t)t * NSAMP];
    }

    // ---- gather batch A (samples wv*8 + {0..3}) issue: coalesced 256-B rows,
    // half-wave s2 per sample, uint2 = 4 channels per lane ----
    const int s2  = lane >> 5;
    const int ch4 = (lane & 31) * 4;
    const unsigned short* fb = f2dt + (size_t)b * HW * C2D + ch4;
    uint2  ga[2][4];
    float4 wA[2];
    #pragma unroll
    for (int i = 0; i < 2; ++i) {
        const int src = i * 2 + s2;
        int4 o;
        o.x = __shfl(o4x, src); o.y = __shfl(o4y, src);
        o.z = __shfl(o4z, src); o.w = __shfl(o4w, src);
        wA[i].x = __shfl(w4x, src); wA[i].y = __shfl(w4y, src);
        wA[i].z = __shfl(w4z, src); wA[i].w = __shfl(w4w, src);
        ga[i][0] = *(const uint2*)(fb + (size_t)o.x * C2D);
        ga[i][1] = *(const uint2*)(fb + (size_t)o.y * C2D);
        ga[i][2] = *(const uint2*)(fb + (size_t)o.z * C2D);
        ga[i][3] = *(const uint2*)(fb + (size_t)o.w * C2D);
    }

    // ---- pack f3d -> cat[n][128 + 16wv .. +16] (covers gather-A latency) ----
    {
        uint4 pk0, pk1;
        pk0.x = pack2(v3[0],  v3[1]);  pk0.y = pack2(v3[2],  v3[3]);
        pk0.z = pack2(v3[4],  v3[5]);  pk0.w = pack2(v3[6],  v3[7]);
        pk1.x = pack2(v3[8],  v3[9]);  pk1.y = pack2(v3[10], v3[11]);
        pk1.z = pack2(v3[12], v3[13]); pk1.w = pack2(v3[14], v3[15]);
        *(uint4*)&catw[lane * (CATS / 2) + (C2D / 2) + wv * 8]     = pk0;
        *(uint4*)&catw[lane * (CATS / 2) + (C2D / 2) + wv * 8 + 4] = pk1;
    }
    __syncthreads();   // bar1: k-half2 ready (also drains batch-A loads)

    const int quad = lane >> 4;
    const int nloc = lane & 15;
    const int mwv  = (wv & 3) * 32;        // co slice base
    const int nwv  = (wv >> 2) * 32;       // sample half base

    f32x4 acc[2][2];
    #pragma unroll
    for (int mt = 0; mt < 2; ++mt)
        #pragma unroll
        for (int nt = 0; nt < 2; ++nt)
            acc[mt][nt] = (f32x4){0.f, 0.f, 0.f, 0.f};

    const unsigned short* wb0 = Wb + (size_t)(mwv + nloc) * KK + quad * 8;

    // ---- GEMM k-half2 (f3d channels, k = 128..255) ----
    #pragma unroll
    for (int ks = 4; ks < 8; ++ks) {
        const int k0 = ks * 32;
        const bf16x8 a0 = *(const bf16x8*)(wb0 + k0);
        const bf16x8 a1 = *(const bf16x8*)(wb0 + 16 * KK + k0);
        #pragma unroll
        for (int nt = 0; nt < 2; ++nt) {
            const bf16x8 bf = *(const bf16x8*)
                &cat[(nwv + nt * 16 + nloc) * CATS + k0 + quad * 8];
            acc[0][nt] = __builtin_amdgcn_mfma_f32_16x16x32_bf16(a0, bf, acc[0][nt], 0, 0, 0);
            acc[1][nt] = __builtin_amdgcn_mfma_f32_16x16x32_bf16(a1, bf, acc[1][nt], 0, 0, 0);
        }
    }

    // ---- issue gather batch B under blend of batch A ----
    uint2  gb[2][4];
    float4 wB[2];
    #pragma unroll
    for (int i = 0; i < 2; ++i) {
        const int src = (i + 2) * 2 + s2;
        int4 o;
        o.x = __shfl(o4x, src); o.y = __shfl(o4y, src);
        o.z = __shfl(o4z, src); o.w = __shfl(o4w, src);
        wB[i].x = __shfl(w4x, src); wB[i].y = __shfl(w4y, src);
        wB[i].z = __shfl(w4z, src); wB[i].w = __shfl(w4w, src);
        gb[i][0] = *(const uint2*)(fb + (size_t)o.x * C2D);
        gb[i][1] = *(const uint2*)(fb + (size_t)o.y * C2D);
        gb[i][2] = *(const uint2*)(fb + (size_t)o.z * C2D);
        gb[i][3] = *(const uint2*)(fb + (size_t)o.w * C2D);
        blend_write(ga[i], wA[i], catw, wv * 8 + i * 2 + s2, ch4);
    }
    #pragma unroll
    for (int i = 0; i < 2; ++i) {
        blend_write(gb[i], wB[i], catw, wv * 8 + (i + 2) * 2 + s2, ch4);
    }
    __syncthreads();   // bar2: k-half1 (gathered 2D) ready

    // ---- GEMM k-half1 (k = 0..127) ----
    #pragma unroll
    for (int ks = 0; ks < 4; ++ks) {
        const int k0 = ks * 32;
        const bf16x8 a0 = *(const bf16x8*)(wb0 + k0);
        const bf16x8 a1 = *(const bf16x8*)(wb0 + 16 * KK + k0);
        #pragma unroll
        for (int nt = 0; nt < 2; ++nt) {
            const bf16x8 bf = *(const bf16x8*)
                &cat[(nwv + nt * 16 + nloc) * CATS + k0 + quad * 8];
            acc[0][nt] = __builtin_amdgcn_mfma_f32_16x16x32_bf16(a0, bf, acc[0][nt], 0, 0, 0);
            acc[1][nt] = __builtin_amdgcn_mfma_f32_16x16x32_bf16(a1, bf, acc[1][nt], 0, 0, 0);
        }
    }

    // ---- Epilogue: bias + leaky-relu; C/D layout col=lane&15, row=quad*4+r ----
    #pragma unroll
    for (int mt = 0; mt < 2; ++mt) {
        const int cobase = mwv + mt * 16 + quad * 4;
        float bv[4];
        #pragma unroll
        for (int r = 0; r < 4; ++r) bv[r] = bias[cobase + r];
        #pragma unroll
        for (int nt = 0; nt < 2; ++nt) {
            float* po = out + (size_t)(b * COUT + cobase) * NSAMP
                      + n0 + nwv + nt * 16 + nloc;
            #pragma unroll
            for (int r = 0; r < 4; ++r) {
                float yv = acc[mt][nt][r] + bv[r];
                yv = (yv >= 0.0f) ? yv : 0.1f * yv;
                po[(size_t)r * NSAMP] = yv;
            }
        }
    }
}

extern "C" void kernel_launch(void* const* d_in, const int* in_sizes, int n_in,
                              void* d_out, int out_size, void* d_ws, size_t ws_size,
                              hipStream_t stream) {
    const float* xy   = (const float*)d_in[0];
    const float* f2d  = (const float*)d_in[1];
    const float* f3d  = (const float*)d_in[2];
    const float* Wm   = (const float*)d_in[3];
    const float* bias = (const float*)d_in[4];
    float* out = (float*)d_out;

    // ws layout: f2dt bf16 [B*HW*C2D] (15.73 MB), then Wb bf16 [COUT*KK]
    unsigned short* f2dt = (unsigned short*)d_ws;
    unsigned short* Wb   = f2dt + (size_t)BB * HW * C2D;

    wcvt_kernel<<<dim3((COUT * KK / 4) / 256), 256, 0, stream>>>(Wm, Wb);
    transpose_cvt_kernel<<<dim3(BB * (HW / 128)), 512, 0, stream>>>(f2d, f2dt);
    fuse_kernel<<<dim3(BB * (NSAMP / TN)), 512, 0, stream>>>(
        xy, f2dt, f3d, Wb, bias, out);
}

// Round 5
// 128.825 us; speedup vs baseline: 1.2948x; 1.0514x over previous
//
#include <hip/hip_runtime.h>
#include <hip/hip_bf16.h>

// Problem constants (fixed by setup_inputs)
#define NSAMP 16384   // N
#define BB    4       // batch
#define C2D   128
#define C3D   128
#define HH    96
#define WW    160
#define COUT  128
#define KK    256     // fan_in
#define HW    (HH*WW) // 15360
#define TN    64      // samples per fuse block
#define CATS  264     // cat row stride bf16: word stride 132 == 4 (mod 32) -> 2-way (free)
                      // on b128 quarter-wave access, 16B-aligned rows
#define TS    136     // transpose LDS row stride shorts: word stride 68

typedef __attribute__((ext_vector_type(8))) short bf16x8;  // 8 bf16 = 4 VGPRs (MFMA A/B frag)
typedef __attribute__((ext_vector_type(4))) float f32x4;   // MFMA C/D frag

__device__ __forceinline__ float bf16lo(unsigned int u) { return __uint_as_float(u << 16); }
__device__ __forceinline__ float bf16hi(unsigned int u) { return __uint_as_float(u & 0xffff0000u); }
__device__ __forceinline__ unsigned int pack2(float a, float b) {
    union { __hip_bfloat162 h; unsigned int u; } c;
    c.h = __float22bfloat162_rn(make_float2(a, b));   // RNE, x in low 16 bits
    return c.u;
}

// ---------------------------------------------------------------------------
// Kernel 1: W fp32 [COUT,KK] -> bf16 row-major (A-fragment-friendly).
// ---------------------------------------------------------------------------
__global__ __launch_bounds__(256) void wcvt_kernel(
    const float* __restrict__ Wm, unsigned short* __restrict__ Wb)
{
    const int i = blockIdx.x * 256 + threadIdx.x;   // 8192 threads x 4 elems
    const float4 v = ((const float4*)Wm)[i];
    uint2 o;
    o.x = pack2(v.x, v.y);
    o.y = pack2(v.z, v.w);
    ((uint2*)Wb)[i] = o;
}

// ---------------------------------------------------------------------------
// Kernel 2: f2d fp32 [B,C2D,H,W] -> f2dt bf16 channel-last [B,HW,C2D].
// Tile = 128 hw x 128 c, 512 threads, 480 blocks (XCD-swizzled).
// Verified correct in round 4.
// LDS word layout: word(row, w) = row*68 + (w ^ xk(row)), xk = 4*((row>>3)&7):
//   stage b32 writes conflict-free; readout b128 16B-aligned conflict-free.
// ---------------------------------------------------------------------------
__global__ __launch_bounds__(512) void transpose_cvt_kernel(
    const float* __restrict__ f2d, unsigned short* __restrict__ f2dt)
{
    __shared__ unsigned short t[128 * TS];   // 34816 B
    unsigned int* tw = (unsigned int*)t;
    const int tid  = threadIdx.x;
    const int lane = tid & 63;
    const int wv   = tid >> 6;               // 0..7: channels [16wv, 16wv+16)
    const int blk  = (blockIdx.x & 7) * 60 + (blockIdx.x >> 3);  // 480 % 8 == 0
    const int b    = blk / 120;
    const int hw0  = (blk % 120) * 128;

    const int xk = 4 * ((lane >> 3) & 7);    // row-XOR key (rows lane, lane+64 share it)
    const float* src = f2d + (size_t)b * C2D * HW + hw0 + lane;
    #pragma unroll
    for (int st = 0; st < 8; ++st) {
        const int c = wv * 16 + st * 2;
        const float va0 = src[(size_t)c * HW];
        const float vb0 = src[(size_t)(c + 1) * HW];
        const float va1 = src[(size_t)c * HW + 64];
        const float vb1 = src[(size_t)(c + 1) * HW + 64];
        const int w = (c >> 1) ^ xk;
        tw[lane        * (TS / 2) + w] = pack2(va0, vb0);
        tw[(lane + 64) * (TS / 2) + w] = pack2(va1, vb1);
    }
    __syncthreads();
    #pragma unroll
    for (int it = 0; it < 4; ++it) {
        const int r  = it * 32 + (tid >> 4);
        const int rk = 4 * ((r >> 3) & 7);
        const uint4 v = *(const uint4*)&tw[r * (TS / 2) + (((tid & 15) * 4) ^ rk)];
        *(uint4*)&f2dt[((size_t)b * HW + hw0 + r) * C2D + (tid & 15) * 8] = v;
    }
}

// ---------------------------------------------------------------------------
// Kernel 3 helper: blend 4 gathered corner fragments (4 channels each) and
// write the packed bf16 result into the cat LDS row. (Function, not macro:
// a macro parameter named `w` would collide with float4's `.w` member.)
// ---------------------------------------------------------------------------
__device__ __forceinline__ void blend_write(
    const uint2* cv, const float4 bw, unsigned int* catw, int row, int ch4)
{
    float r0 = bw.x * bf16lo(cv[0].x) + bw.y * bf16lo(cv[1].x)
             + bw.z * bf16lo(cv[2].x) + bw.w * bf16lo(cv[3].x);
    float r1 = bw.x * bf16hi(cv[0].x) + bw.y * bf16hi(cv[1].x)
             + bw.z * bf16hi(cv[2].x) + bw.w * bf16hi(cv[3].x);
    float r2 = bw.x * bf16lo(cv[0].y) + bw.y * bf16lo(cv[1].y)
             + bw.z * bf16lo(cv[2].y) + bw.w * bf16lo(cv[3].y);
    float r3 = bw.x * bf16hi(cv[0].y) + bw.y * bf16hi(cv[1].y)
             + bw.z * bf16hi(cv[2].y) + bw.w * bf16hi(cv[3].y);
    uint2 pk;
    pk.x = pack2(r0, r1);
    pk.y = pack2(r2, r3);
    *(uint2*)&catw[row * (CATS / 2) + (ch4 >> 1)] = pk;
}

// ---------------------------------------------------------------------------
// Kernel 3: fused bilinear-gather + concat + bf16 MFMA GEMM + bias + leaky.
// Round-0 shape: 256 threads (4 waves), TN=64, grid 1024 (4 blocks/CU by LDS
// -> 16 waves/CU), acc[2][4] per wave (co 32-slice x all 64 samples).
// New vs round 0:
//  (a) XCD-bijective grid swizzle: each XCD's blocks stay in one batch ->
//      f2dt slice (3.93 MB) resident in that XCD's 4-MB L2.
//  (b) split-K pipeline: gather batch A (8 samples/wave) issued, then the
//      f3d-half GEMM (16 MFMA) runs while those loads are in flight; batch B
//      issued under the blend of A; single extra cost is ~48 live VGPRs.
// launch_bounds (256,4): VGPR cap 128, 4 waves/EU.
// ---------------------------------------------------------------------------
__global__ __launch_bounds__(256, 4) void fuse_kernel(
    const float*          __restrict__ xy,     // [B,2,N]
    const unsigned short* __restrict__ f2dt,   // [B,HW,C2D] bf16
    const float*          __restrict__ f3d,    // [B,C3D,N]
    const unsigned short* __restrict__ Wb,     // [COUT,KK] bf16
    const float*          __restrict__ bias,   // [COUT]
    float* __restrict__ out)                   // [B,COUT,N]
{
    __shared__ unsigned short cat[TN * CATS];  // 33792 B
    __shared__ float4 sw4[TN];
    __shared__ int4   soff4[TN];
    unsigned int* catw = (unsigned int*)cat;

    const int tid  = threadIdx.x;
    const int lane = tid & 63;
    const int wv   = tid >> 6;                 // 0..3
    // XCD-bijective swizzle (1024 % 8 == 0)
    const int blk  = (blockIdx.x & 7) * 128 + (blockIdx.x >> 3);
    const int b    = blk >> 8;                 // 256 tiles per batch
    const int n0   = (blk & 255) * TN;

    // ---- Phase 0: bilinear params (wave 0) ----
    if (tid < TN) {
        const int n = n0 + tid;
        float x = xy[((size_t)b * 2 + 0) * NSAMP + n];
        float y = xy[((size_t)b * 2 + 1) * NSAMP + n];
        float xf = floorf(x), yf = floorf(y);
        float wx1 = x - xf, wy1 = y - yf;
        float wx0 = 1.0f - wx1, wy0 = 1.0f - wy1;
        int x0 = (int)xf, y0 = (int)yf;
        int x1 = x0 + 1, y1 = y0 + 1;
        if (x0 < 0 || x0 > WW - 1) wx0 = 0.0f;
        if (x1 < 0 || x1 > WW - 1) wx1 = 0.0f;
        if (y0 < 0 || y0 > HH - 1) wy0 = 0.0f;
        if (y1 < 0 || y1 > HH - 1) wy1 = 0.0f;
        x0 = min(max(x0, 0), WW - 1);
        x1 = min(max(x1, 0), WW - 1);
        y0 = min(max(y0, 0), HH - 1);
        y1 = min(max(y1, 0), HH - 1);
        sw4[tid]   = make_float4(wx0 * wy0, wx1 * wy0, wx0 * wy1, wx1 * wy1);
        soff4[tid] = make_int4(y0 * WW + x0, y0 * WW + x1,
                               y1 * WW + x0, y1 * WW + x1);
    }

    // ---- Phase 1a: f3d -> cat[n][128+c], bf16. lane = sample, wave wv covers
    // 32 channels. Coalesced 4B loads; b128 LDS writes (2-way, free). ----
    {
        const float* p3 = f3d + (size_t)(b * C3D) * NSAMP + n0 + lane;
        #pragma unroll
        for (int ch = 0; ch < 4; ++ch) {
            const int cbase = wv * 32 + ch * 8;
            float v[8];
            #pragma unroll
            for (int t = 0; t < 8; ++t) v[t] = p3[(size_t)(cbase + t) * NSAMP];
            uint4 pk;
            pk.x = pack2(v[0], v[1]);
            pk.y = pack2(v[2], v[3]);
            pk.z = pack2(v[4], v[5]);
            pk.w = pack2(v[6], v[7]);
            *(uint4*)&catw[lane * (CATS / 2) + (C2D / 2) + (cbase >> 1)] = pk;
        }
    }
    __syncthreads();   // bar1: params + f3d-half of cat ready

    const int quad = lane >> 4;
    const int nloc = lane & 15;
    const int s2   = lane >> 5;
    const int ch4  = (lane & 31) * 4;
    const unsigned short* fb = f2dt + (size_t)b * HW * C2D + ch4;

    // ---- issue gather batch A: samples wv*16 + {0..7}, half-wave s2 per
    // sample, uint2 = 4 channels per lane, coalesced 256-B rows ----
    uint2  ga[4][4];
    float4 wA[4];
    #pragma unroll
    for (int i = 0; i < 4; ++i) {
        const int j = wv * 16 + i * 2 + s2;
        const int4 o = soff4[j];               // LDS broadcast (uniform per half-wave)
        wA[i] = sw4[j];
        ga[i][0] = *(const uint2*)(fb + (size_t)o.x * C2D);
        ga[i][1] = *(const uint2*)(fb + (size_t)o.y * C2D);
        ga[i][2] = *(const uint2*)(fb + (size_t)o.z * C2D);
        ga[i][3] = *(const uint2*)(fb + (size_t)o.w * C2D);
    }

    f32x4 acc[2][4];
    #pragma unroll
    for (int mt = 0; mt < 2; ++mt)
        #pragma unroll
        for (int nt = 0; nt < 4; ++nt)
            acc[mt][nt] = (f32x4){0.f, 0.f, 0.f, 0.f};

    // A-fragment base: row co = 32wv + mt*16 + nloc, k = k0 + quad*8 + j
    const unsigned short* wb0 = Wb + (size_t)(wv * 32 + nloc) * KK + quad * 8;

    // ---- GEMM k-half2 (f3d channels, k = 128..255) — covers batch-A flight ----
    #pragma unroll
    for (int ks = 4; ks < 8; ++ks) {
        const int k0 = ks * 32;
        const bf16x8 a0 = *(const bf16x8*)(wb0 + k0);
        const bf16x8 a1 = *(const bf16x8*)(wb0 + 16 * KK + k0);
        #pragma unroll
        for (int nt = 0; nt < 4; ++nt) {
            const bf16x8 bfrag = *(const bf16x8*)
                &cat[(nt * 16 + nloc) * CATS + k0 + quad * 8];
            acc[0][nt] = __builtin_amdgcn_mfma_f32_16x16x32_bf16(
                a0, bfrag, acc[0][nt], 0, 0, 0);
            acc[1][nt] = __builtin_amdgcn_mfma_f32_16x16x32_bf16(
                a1, bfrag, acc[1][nt], 0, 0, 0);
        }
    }

    // ---- blend batch A while issuing batch B (samples wv*16 + {8..15}) ----
    #pragma unroll
    for (int i = 0; i < 4; ++i) {
        const int j2 = wv * 16 + 8 + i * 2 + s2;
        const int4 o = soff4[j2];
        const float4 wv4 = sw4[j2];
        uint2 gb[4];
        gb[0] = *(const uint2*)(fb + (size_t)o.x * C2D);
        gb[1] = *(const uint2*)(fb + (size_t)o.y * C2D);
        gb[2] = *(const uint2*)(fb + (size_t)o.z * C2D);
        gb[3] = *(const uint2*)(fb + (size_t)o.w * C2D);
        blend_write(ga[i], wA[i], catw, wv * 16 + i * 2 + s2, ch4);
        blend_write(gb, wv4, catw, j2, ch4);
    }
    __syncthreads();   // bar2: 2D-half of cat ready

    // ---- GEMM k-half1 (gathered 2D, k = 0..127) ----
    #pragma unroll
    for (int ks = 0; ks < 4; ++ks) {
        const int k0 = ks * 32;
        const bf16x8 a0 = *(const bf16x8*)(wb0 + k0);
        const bf16x8 a1 = *(const bf16x8*)(wb0 + 16 * KK + k0);
        #pragma unroll
        for (int nt = 0; nt < 4; ++nt) {
            const bf16x8 bfrag = *(const bf16x8*)
                &cat[(nt * 16 + nloc) * CATS + k0 + quad * 8];
            acc[0][nt] = __builtin_amdgcn_mfma_f32_16x16x32_bf16(
                a0, bfrag, acc[0][nt], 0, 0, 0);
            acc[1][nt] = __builtin_amdgcn_mfma_f32_16x16x32_bf16(
                a1, bfrag, acc[1][nt], 0, 0, 0);
        }
    }

    // ---- Epilogue: bias + leaky-relu; C/D layout col=lane&15, row=quad*4+r ----
    #pragma unroll
    for (int mt = 0; mt < 2; ++mt) {
        const int cobase = wv * 32 + mt * 16 + quad * 4;
        float bv[4];
        #pragma unroll
        for (int r = 0; r < 4; ++r) bv[r] = bias[cobase + r];
        #pragma unroll
        for (int nt = 0; nt < 4; ++nt) {
            float* po = out + (size_t)(b * COUT + cobase) * NSAMP
                      + n0 + nt * 16 + nloc;
            #pragma unroll
            for (int r = 0; r < 4; ++r) {
                float yv = acc[mt][nt][r] + bv[r];
                yv = (yv >= 0.0f) ? yv : 0.1f * yv;
                po[(size_t)r * NSAMP] = yv;
            }
        }
    }
}

extern "C" void kernel_launch(void* const* d_in, const int* in_sizes, int n_in,
                              void* d_out, int out_size, void* d_ws, size_t ws_size,
                              hipStream_t stream) {
    const float* xy   = (const float*)d_in[0];
    const float* f2d  = (const float*)d_in[1];
    const float* f3d  = (const float*)d_in[2];
    const float* Wm   = (const float*)d_in[3];
    const float* bias = (const float*)d_in[4];
    float* out = (float*)d_out;

    // ws layout: f2dt bf16 [B*HW*C2D] (15.73 MB), then Wb bf16 [COUT*KK]
    unsigned short* f2dt = (unsigned short*)d_ws;
    unsigned short* Wb   = f2dt + (size_t)BB * HW * C2D;

    wcvt_kernel<<<dim3((COUT * KK / 4) / 256), 256, 0, stream>>>(Wm, Wb);
    transpose_cvt_kernel<<<dim3(BB * (HW / 128)), 512, 0, stream>>>(f2d, f2dt);
    fuse_kernel<<<dim3(BB * (NSAMP / TN)), 256, 0, stream>>>(
        xy, f2dt, f3d, Wb, bias, out);
}

// Round 6
// 126.242 us; speedup vs baseline: 1.3213x; 1.0205x over previous
//
#include <hip/hip_runtime.h>
#include <hip/hip_bf16.h>

// Problem constants (fixed by setup_inputs)
#define NSAMP 16384   // N
#define BB    4       // batch
#define C2D   128
#define C3D   128
#define HH    96
#define WW    160
#define COUT  128
#define KK    256     // fan_in
#define HW    (HH*WW) // 15360
#define TN    64      // samples per fuse block
#define CATS  264     // cat row stride bf16: word stride 132 == 4 (mod 32);
                      // b128 frag reads and uint2 blend writes both hit the
                      // per-access minimum pass count (conflict-free)
#define TS    136     // transpose LDS row stride shorts: word stride 68

typedef __attribute__((ext_vector_type(8))) short bf16x8;  // 8 bf16 = 4 VGPRs (MFMA A/B frag)
typedef __attribute__((ext_vector_type(4))) float f32x4;   // MFMA C/D frag

__device__ __forceinline__ float bf16lo(unsigned int u) { return __uint_as_float(u << 16); }
__device__ __forceinline__ float bf16hi(unsigned int u) { return __uint_as_float(u & 0xffff0000u); }
__device__ __forceinline__ unsigned int pack2(float a, float b) {
    union { __hip_bfloat162 h; unsigned int u; } c;
    c.h = __float22bfloat162_rn(make_float2(a, b));   // RNE, x in low 16 bits
    return c.u;
}

// ---------------------------------------------------------------------------
// Kernel 1: f2d fp32 [B,C2D,H,W] -> f2dt bf16 channel-last [B,HW,C2D],
// PLUS (blocks 480..495) W fp32 [COUT,KK] -> Wb bf16 row-major (merged to
// save one launch gap; wcvt is 16 blocks x 512 threads = 8192 float4).
// Transpose tile = 128 hw x 128 c, 512 threads, 480 blocks (XCD-swizzled).
// Verified correct in rounds 4/5.
// LDS word layout: word(row, w) = row*68 + (w ^ xk(row)), xk = 4*((row>>3)&7):
//   stage b32 writes conflict-free; readout b128 16B-aligned conflict-free.
// ---------------------------------------------------------------------------
__global__ __launch_bounds__(512) void transpose_cvt_kernel(
    const float* __restrict__ f2d, unsigned short* __restrict__ f2dt,
    const float* __restrict__ Wm,  unsigned short* __restrict__ Wb)
{
    __shared__ unsigned short t[128 * TS];   // 34816 B
    const int raw = blockIdx.x;
    if (raw >= 480) {                        // merged wcvt tail blocks
        const int i = (raw - 480) * 512 + threadIdx.x;   // 8192 float4 total
        const float4 v = ((const float4*)Wm)[i];
        uint2 o;
        o.x = pack2(v.x, v.y);
        o.y = pack2(v.z, v.w);
        ((uint2*)Wb)[i] = o;
        return;
    }
    unsigned int* tw = (unsigned int*)t;
    const int tid  = threadIdx.x;
    const int lane = tid & 63;
    const int wv   = tid >> 6;               // 0..7: channels [16wv, 16wv+16)
    const int blk  = (raw & 7) * 60 + (raw >> 3);   // 480 % 8 == 0, bijective
    const int b    = blk / 120;
    const int hw0  = (blk % 120) * 128;

    const int xk = 4 * ((lane >> 3) & 7);    // row-XOR key (rows lane, lane+64 share it)
    const float* src = f2d + (size_t)b * C2D * HW + hw0 + lane;
    #pragma unroll
    for (int st = 0; st < 8; ++st) {
        const int c = wv * 16 + st * 2;
        const float va0 = src[(size_t)c * HW];
        const float vb0 = src[(size_t)(c + 1) * HW];
        const float va1 = src[(size_t)c * HW + 64];
        const float vb1 = src[(size_t)(c + 1) * HW + 64];
        const int w = (c >> 1) ^ xk;
        tw[lane        * (TS / 2) + w] = pack2(va0, vb0);
        tw[(lane + 64) * (TS / 2) + w] = pack2(va1, vb1);
    }
    __syncthreads();
    #pragma unroll
    for (int it = 0; it < 4; ++it) {
        const int r  = it * 32 + (tid >> 4);
        const int rk = 4 * ((r >> 3) & 7);
        const uint4 v = *(const uint4*)&tw[r * (TS / 2) + (((tid & 15) * 4) ^ rk)];
        *(uint4*)&f2dt[((size_t)b * HW + hw0 + r) * C2D + (tid & 15) * 8] = v;
    }
}

// ---------------------------------------------------------------------------
// Kernel 2 helper: blend 4 gathered corner fragments (4 channels each) and
// write the packed bf16 result into the cat LDS row. (Function, not macro:
// a macro parameter named `w` would collide with float4's `.w` member.)
// Write pattern: uint2 per lane, 128 words/wave over 32 banks = 4 passes,
// distribution exactly 4 words/bank -> minimum (conflict-free).
// ---------------------------------------------------------------------------
__device__ __forceinline__ void blend_write(
    const uint2* cv, const float4 bw, unsigned int* catw, int row, int ch4)
{
    float r0 = bw.x * bf16lo(cv[0].x) + bw.y * bf16lo(cv[1].x)
             + bw.z * bf16lo(cv[2].x) + bw.w * bf16lo(cv[3].x);
    float r1 = bw.x * bf16hi(cv[0].x) + bw.y * bf16hi(cv[1].x)
             + bw.z * bf16hi(cv[2].x) + bw.w * bf16hi(cv[3].x);
    float r2 = bw.x * bf16lo(cv[0].y) + bw.y * bf16lo(cv[1].y)
             + bw.z * bf16lo(cv[2].y) + bw.w * bf16lo(cv[3].y);
    float r3 = bw.x * bf16hi(cv[0].y) + bw.y * bf16hi(cv[1].y)
             + bw.z * bf16hi(cv[2].y) + bw.w * bf16hi(cv[3].y);
    uint2 pk;
    pk.x = pack2(r0, r1);
    pk.y = pack2(r2, r3);
    *(uint2*)&catw[row * (CATS / 2) + (ch4 >> 1)] = pk;
}

// ---------------------------------------------------------------------------
// Kernel 2: fused bilinear-gather + concat + bf16 MFMA GEMM + bias + leaky.
// 256 threads (4 waves), TN=64, grid 1024 XCD-swizzled, 4 blocks/CU.
// Single-barrier structure:
//   params (registers, per-wave redundant) -> issue gather A -> f3d load+pack
//   (covers A's flight) -> issue gather B -> blend A (covers B's flight) ->
//   blend B -> ONE __syncthreads -> full K=256 GEMM (32 MFMA unbroken) ->
//   bias + leaky epilogue.
// Lane L holds params of sample wv*16 + (L&15); __shfl distributes to the
// half-wave (s2) that gathers each sample. No params LDS, no wave-0 phase.
// launch_bounds (256,4): VGPR cap 128 (est. peak ~110: ga+gb 64 + misc).
// ---------------------------------------------------------------------------
__global__ __launch_bounds__(256, 4) void fuse_kernel(
    const float*          __restrict__ xy,     // [B,2,N]
    const unsigned short* __restrict__ f2dt,   // [B,HW,C2D] bf16
    const float*          __restrict__ f3d,    // [B,C3D,N]
    const unsigned short* __restrict__ Wb,     // [COUT,KK] bf16
    const float*          __restrict__ bias,   // [COUT]
    float* __restrict__ out)                   // [B,COUT,N]
{
    __shared__ unsigned short cat[TN * CATS];  // 33792 B (only LDS)
    unsigned int* catw = (unsigned int*)cat;

    const int tid  = threadIdx.x;
    const int lane = tid & 63;
    const int wv   = tid >> 6;                 // 0..3
    // XCD-bijective swizzle (1024 % 8 == 0): one XCD's blocks stay in one
    // batch -> f2dt slice (3.93 MB) resident in that XCD's 4-MB L2.
    const int blk  = (blockIdx.x & 7) * 128 + (blockIdx.x >> 3);
    const int b    = blk >> 8;                 // 256 tiles per batch
    const int n0   = (blk & 255) * TN;

    // ---- bilinear params in registers: lane holds sample wv*16 + (lane&15).
    // 4x redundant across quads; xy loads are 64B runs, L1-broadcast. ----
    float w4x, w4y, w4z, w4w;
    int   o4x, o4y, o4z, o4w;
    {
        const int n = n0 + wv * 16 + (lane & 15);
        float x = xy[((size_t)b * 2 + 0) * NSAMP + n];
        float y = xy[((size_t)b * 2 + 1) * NSAMP + n];
        float xf = floorf(x), yf = floorf(y);
        float wx1 = x - xf, wy1 = y - yf;
        float wx0 = 1.0f - wx1, wy0 = 1.0f - wy1;
        int x0 = (int)xf, y0 = (int)yf;
        int x1 = x0 + 1, y1 = y0 + 1;
        if (x0 < 0 || x0 > WW - 1) wx0 = 0.0f;
        if (x1 < 0 || x1 > WW - 1) wx1 = 0.0f;
        if (y0 < 0 || y0 > HH - 1) wy0 = 0.0f;
        if (y1 < 0 || y1 > HH - 1) wy1 = 0.0f;
        x0 = min(max(x0, 0), WW - 1);
        x1 = min(max(x1, 0), WW - 1);
        y0 = min(max(y0, 0), HH - 1);
        y1 = min(max(y1, 0), HH - 1);
        w4x = wx0 * wy0; w4y = wx1 * wy0; w4z = wx0 * wy1; w4w = wx1 * wy1;
        o4x = y0 * WW + x0; o4y = y0 * WW + x1;
        o4z = y1 * WW + x0; o4w = y1 * WW + x1;
    }

    const int s2  = lane >> 5;                 // half-wave id
    const int ch4 = (lane & 31) * 4;           // 4 channels per lane
    const unsigned short* fb = f2dt + (size_t)b * HW * C2D + ch4;

    // ---- issue gather batch A: half-wave s2 covers samples wv*16 + i*2+s2,
    // uint2 = 4 channels/lane, each corner row a 256-B coalesced run ----
    uint2 ga[4][4];
    #pragma unroll
    for (int i = 0; i < 4; ++i) {
        const int jl = i * 2 + s2;             // 0..7
        int4 o;
        o.x = __shfl(o4x, jl); o.y = __shfl(o4y, jl);
        o.z = __shfl(o4z, jl); o.w = __shfl(o4w, jl);
        ga[i][0] = *(const uint2*)(fb + (size_t)o.x * C2D);
        ga[i][1] = *(const uint2*)(fb + (size_t)o.y * C2D);
        ga[i][2] = *(const uint2*)(fb + (size_t)o.z * C2D);
        ga[i][3] = *(const uint2*)(fb + (size_t)o.w * C2D);
    }

    // ---- f3d -> cat[n][128+c] (covers batch-A flight). lane = sample,
    // wave wv covers 32 channels; coalesced 4B loads, b128 LDS writes. ----
    {
        const float* p3 = f3d + (size_t)(b * C3D) * NSAMP + n0 + lane;
        #pragma unroll
        for (int ch = 0; ch < 4; ++ch) {
            const int cbase = wv * 32 + ch * 8;
            float v[8];
            #pragma unroll
            for (int t = 0; t < 8; ++t) v[t] = p3[(size_t)(cbase + t) * NSAMP];
            uint4 pk;
            pk.x = pack2(v[0], v[1]);
            pk.y = pack2(v[2], v[3]);
            pk.z = pack2(v[4], v[5]);
            pk.w = pack2(v[6], v[7]);
            *(uint4*)&catw[lane * (CATS / 2) + (C2D / 2) + (cbase >> 1)] = pk;
        }
    }

    // ---- issue gather batch B: samples wv*16 + 8 + i*2+s2 ----
    uint2 gb[4][4];
    #pragma unroll
    for (int i = 0; i < 4; ++i) {
        const int jl = 8 + i * 2 + s2;         // 8..15
        int4 o;
        o.x = __shfl(o4x, jl); o.y = __shfl(o4y, jl);
        o.z = __shfl(o4z, jl); o.w = __shfl(o4w, jl);
        gb[i][0] = *(const uint2*)(fb + (size_t)o.x * C2D);
        gb[i][1] = *(const uint2*)(fb + (size_t)o.y * C2D);
        gb[i][2] = *(const uint2*)(fb + (size_t)o.z * C2D);
        gb[i][3] = *(const uint2*)(fb + (size_t)o.w * C2D);
    }

    // ---- blend A (VALU, covers batch-B flight), then blend B ----
    #pragma unroll
    for (int i = 0; i < 4; ++i) {
        const int jl = i * 2 + s2;
        float4 bw;
        bw.x = __shfl(w4x, jl); bw.y = __shfl(w4y, jl);
        bw.z = __shfl(w4z, jl); bw.w = __shfl(w4w, jl);
        blend_write(ga[i], bw, catw, wv * 16 + jl, ch4);
    }
    #pragma unroll
    for (int i = 0; i < 4; ++i) {
        const int jl = 8 + i * 2 + s2;
        float4 bw;
        bw.x = __shfl(w4x, jl); bw.y = __shfl(w4y, jl);
        bw.z = __shfl(w4z, jl); bw.w = __shfl(w4w, jl);
        blend_write(gb[i], bw, catw, wv * 16 + jl, ch4);
    }
    __syncthreads();   // the ONLY barrier: full cat tile ready

    // ---- GEMM: D[128 x 64] = Wb[128 x 256] @ cat^T, 32 unbroken MFMA ----
    const int quad = lane >> 4;
    const int nloc = lane & 15;

    f32x4 acc[2][4];
    #pragma unroll
    for (int mt = 0; mt < 2; ++mt)
        #pragma unroll
        for (int nt = 0; nt < 4; ++nt)
            acc[mt][nt] = (f32x4){0.f, 0.f, 0.f, 0.f};

    // A-fragment base: row co = 32wv + mt*16 + nloc, k = k0 + quad*8 + j
    const unsigned short* wb0 = Wb + (size_t)(wv * 32 + nloc) * KK + quad * 8;

    #pragma unroll 2
    for (int ks = 0; ks < 8; ++ks) {
        const int k0 = ks * 32;
        const bf16x8 a0 = *(const bf16x8*)(wb0 + k0);
        const bf16x8 a1 = *(const bf16x8*)(wb0 + 16 * KK + k0);
        #pragma unroll
        for (int nt = 0; nt < 4; ++nt) {
            const bf16x8 bfrag = *(const bf16x8*)
                &cat[(nt * 16 + nloc) * CATS + k0 + quad * 8];
            acc[0][nt] = __builtin_amdgcn_mfma_f32_16x16x32_bf16(
                a0, bfrag, acc[0][nt], 0, 0, 0);
            acc[1][nt] = __builtin_amdgcn_mfma_f32_16x16x32_bf16(
                a1, bfrag, acc[1][nt], 0, 0, 0);
        }
    }

    // ---- Epilogue: bias + leaky-relu; C/D layout col=lane&15, row=quad*4+r ----
    #pragma unroll
    for (int mt = 0; mt < 2; ++mt) {
        const int cobase = wv * 32 + mt * 16 + quad * 4;
        float bv[4];
        #pragma unroll
        for (int r = 0; r < 4; ++r) bv[r] = bias[cobase + r];
        #pragma unroll
        for (int nt = 0; nt < 4; ++nt) {
            float* po = out + (size_t)(b * COUT + cobase) * NSAMP
                      + n0 + nt * 16 + nloc;
            #pragma unroll
            for (int r = 0; r < 4; ++r) {
                float yv = acc[mt][nt][r] + bv[r];
                yv = (yv >= 0.0f) ? yv : 0.1f * yv;
                po[(size_t)r * NSAMP] = yv;
            }
        }
    }
}

extern "C" void kernel_launch(void* const* d_in, const int* in_sizes, int n_in,
                              void* d_out, int out_size, void* d_ws, size_t ws_size,
                              hipStream_t stream) {
    const float* xy   = (const float*)d_in[0];
    const float* f2d  = (const float*)d_in[1];
    const float* f3d  = (const float*)d_in[2];
    const float* Wm   = (const float*)d_in[3];
    const float* bias = (const float*)d_in[4];
    float* out = (float*)d_out;

    // ws layout: f2dt bf16 [B*HW*C2D] (15.73 MB), then Wb bf16 [COUT*KK]
    unsigned short* f2dt = (unsigned short*)d_ws;
    unsigned short* Wb   = f2dt + (size_t)BB * HW * C2D;

    // 480 transpose blocks + 16 wcvt blocks in one launch
    transpose_cvt_kernel<<<dim3(496), 512, 0, stream>>>(f2d, f2dt, Wm, Wb);
    fuse_kernel<<<dim3(BB * (NSAMP / TN)), 256, 0, stream>>>(
        xy, f2dt, f3d, Wb, bias, out);
}